// Round 6
// baseline (218.668 us; speedup 1.0000x reference)
//
#include <hip/hip_runtime.h>

// out[o,i,h,w] = sum_k weights[o,i,k] * x[k,h,w]
// weights: (2048, 2048, 3) fp32   x: (3, 3, 3) fp32   out: (2048, 2048, 3, 3) fp32
//
// Memory-bound: 50.3 MB read + 151 MB write, ~190 MFLOP. Roofline ~32-38 us
// (202 MB @ 5.3-6.3 TB/s mixed).
//
// V5 = V4 body, launched TWICE per kernel_launch (idempotent: second launch
// rewrites identical values). DECOMPOSITION EXPERIMENT: dur_us has a large
// harness floor (poison fills of 604 MB @ ~6.8 TB/s dominate the profile;
// gf_kernel < 88 us since it never makes top-5; 4 structurally different
// kernels all measured 185-191 us). dur_us(V5) - dur_us(V4) = one kernel
// execution. Delta < 45 us -> kernel is at the HBM roofline and the rest is
// harness floor; delta > 60 us -> real headroom exists.
//
// V4 structure: full occupancy. PPT=2 -> 18,432 B LDS/block -> 8 blocks/CU =
// 32 waves/CU; __launch_bounds__(256,8) caps VGPR at 64.
//   - per thread: 2 pairs, 6 weight floats as 3 x f32x2 (24 B, 8B-aligned)
//   - 18 outputs in registers (fully unrolled, static indices)
//   - stage as 9 x ds_write_b64: bank pair (18t+2j)%32, perfectly even
//   - flush: 1152 f32x4/block, 4 coalesced rounds + 128-lane tail, cached
// Exact cover: 8192 blocks * 18,432 B = 150,994,944 B = out size.

typedef float f32x2 __attribute__((ext_vector_type(2)));
typedef float f32x4 __attribute__((ext_vector_type(4)));

#define THREADS 256
#define PPT 2
#define PAIRS_PER_BLOCK (THREADS * PPT)                 // 512
#define OUT_FLOATS_PER_BLOCK (PAIRS_PER_BLOCK * 9)      // 4608 floats = 18432 B
#define OUT_F4_PER_BLOCK (OUT_FLOATS_PER_BLOCK / 4)     // 1152

__global__ __launch_bounds__(THREADS, 8) void gf_kernel(const float* __restrict__ x,
                                                        const float* __restrict__ w,
                                                        float* __restrict__ out) {
    __shared__ __align__(16) float so[OUT_FLOATS_PER_BLOCK];

    const int t = threadIdx.x;
    const size_t g = (size_t)blockIdx.x * THREADS + t;  // global thread id

    // 6 contiguous weight floats per thread as 3 x f32x2 (8B-aligned: 24 B * g).
    const f32x2* __restrict__ wv = (const f32x2*)(w + g * 6);
    const f32x2 l0 = wv[0];
    const f32x2 l1 = wv[1];
    const f32x2 l2 = wv[2];

    // x is 27 floats, wave-uniform -> scalar loads, cache-served.
    float xv[27];
#pragma unroll
    for (int i = 0; i < 27; ++i) xv[i] = x[i];

    // Pair A weights: (l0.x, l0.y, l1.x); pair B: (l1.y, l2.x, l2.y).
    float o[18];
#pragma unroll
    for (int hw = 0; hw < 9; ++hw) {
        o[hw]     = l0.x * xv[hw] + l0.y * xv[9 + hw] + l1.x * xv[18 + hw];
        o[9 + hw] = l1.y * xv[hw] + l2.x * xv[9 + hw] + l2.y * xv[18 + hw];
    }

    // Stage: thread t owns f32x2-slots [9t, 9t+9) == floats [18t, 18t+18).
    f32x2* __restrict__ sov = (f32x2*)so;
#pragma unroll
    for (int j = 0; j < 9; ++j) {
        f32x2 v = {o[2 * j], o[2 * j + 1]};
        sov[t * 9 + j] = v;
    }

    __syncthreads();

    // Flush: 1152 f32x4 = 4 full rounds of 256 + 128-lane tail; fully coalesced,
    // 16B-aligned, cached write path.
    f32x4* __restrict__ outv = (f32x4*)(out + (size_t)blockIdx.x * OUT_FLOATS_PER_BLOCK);
    const f32x4* __restrict__ s4 = (const f32x4*)so;
#pragma unroll
    for (int i = 0; i < 4; ++i) {
        outv[t + THREADS * i] = s4[t + THREADS * i];
    }
    if (t < OUT_F4_PER_BLOCK - 4 * THREADS) {           // 128 remainder slots
        outv[t + 4 * THREADS] = s4[t + 4 * THREADS];
    }
}

extern "C" void kernel_launch(void* const* d_in, const int* in_sizes, int n_in,
                              void* d_out, int out_size, void* d_ws, size_t ws_size,
                              hipStream_t stream) {
    const float* x = (const float*)d_in[0];   // 27 floats
    const float* w = (const float*)d_in[1];   // 2048*2048*3 floats
    float* out = (float*)d_out;               // 2048*2048*9 floats

    const int pairs = 2048 * 2048;                    // 4,194,304
    const int blocks = pairs / PAIRS_PER_BLOCK;       // 8192, exact cover

    // DOUBLE LAUNCH (decomposition experiment): identical, idempotent work.
    gf_kernel<<<blocks, THREADS, 0, stream>>>(x, w, out);
    gf_kernel<<<blocks, THREADS, 0, stream>>>(x, w, out);
}

// Round 7
// 187.960 us; speedup vs baseline: 1.1634x; 1.1634x over previous
//
#include <hip/hip_runtime.h>

// out[o,i,h,w] = sum_k weights[o,i,k] * x[k,h,w]
// weights: (2048, 2048, 3) fp32   x: (3, 3, 3) fp32   out: (2048, 2048, 3, 3) fp32
//
// ROOFLINE-VERIFIED (round-6 decomposition): double-launch minus single-launch
// = 29.8 us per kernel execution = 202 MB @ ~6.8 TB/s mixed, matching the
// harness fill's own ceiling (6.7-6.9 TB/s). The remaining ~159 us of dur_us
// is fixed harness floor (poison fill + restore in the timed graph; gf_kernel
// never appears in top-5 profiled dispatches, all slots are ~88 us 604 MB
// fills). Structural constraint: HBM write BW on 151 MB of output.
//
// V6 = V4 single launch (revert decomposition experiment).
// Full occupancy: PPT=2 -> 18,432 B LDS/block -> 8 blocks/CU = 32 waves/CU;
// __launch_bounds__(256,8) caps VGPR at 64.
//   - per thread: 2 pairs, 6 weight floats as 3 x f32x2 (24 B, 8B-aligned)
//   - 18 outputs in registers (fully unrolled, static indices)
//   - stage as 9 x ds_write_b64: bank pair (18t+2j)%32, perfectly even
//   - flush: 1152 f32x4/block, 4 coalesced rounds + 128-lane tail, cached
// Exact cover: 8192 blocks * 18,432 B = 150,994,944 B = out size.

typedef float f32x2 __attribute__((ext_vector_type(2)));
typedef float f32x4 __attribute__((ext_vector_type(4)));

#define THREADS 256
#define PPT 2
#define PAIRS_PER_BLOCK (THREADS * PPT)                 // 512
#define OUT_FLOATS_PER_BLOCK (PAIRS_PER_BLOCK * 9)      // 4608 floats = 18432 B
#define OUT_F4_PER_BLOCK (OUT_FLOATS_PER_BLOCK / 4)     // 1152

__global__ __launch_bounds__(THREADS, 8) void gf_kernel(const float* __restrict__ x,
                                                        const float* __restrict__ w,
                                                        float* __restrict__ out) {
    __shared__ __align__(16) float so[OUT_FLOATS_PER_BLOCK];

    const int t = threadIdx.x;
    const size_t g = (size_t)blockIdx.x * THREADS + t;  // global thread id

    // 6 contiguous weight floats per thread as 3 x f32x2 (8B-aligned: 24 B * g).
    const f32x2* __restrict__ wv = (const f32x2*)(w + g * 6);
    const f32x2 l0 = wv[0];
    const f32x2 l1 = wv[1];
    const f32x2 l2 = wv[2];

    // x is 27 floats, wave-uniform -> scalar loads, cache-served.
    float xv[27];
#pragma unroll
    for (int i = 0; i < 27; ++i) xv[i] = x[i];

    // Pair A weights: (l0.x, l0.y, l1.x); pair B: (l1.y, l2.x, l2.y).
    float o[18];
#pragma unroll
    for (int hw = 0; hw < 9; ++hw) {
        o[hw]     = l0.x * xv[hw] + l0.y * xv[9 + hw] + l1.x * xv[18 + hw];
        o[9 + hw] = l1.y * xv[hw] + l2.x * xv[9 + hw] + l2.y * xv[18 + hw];
    }

    // Stage: thread t owns f32x2-slots [9t, 9t+9) == floats [18t, 18t+18).
    f32x2* __restrict__ sov = (f32x2*)so;
#pragma unroll
    for (int j = 0; j < 9; ++j) {
        f32x2 v = {o[2 * j], o[2 * j + 1]};
        sov[t * 9 + j] = v;
    }

    __syncthreads();

    // Flush: 1152 f32x4 = 4 full rounds of 256 + 128-lane tail; fully coalesced,
    // 16B-aligned, cached write path.
    f32x4* __restrict__ outv = (f32x4*)(out + (size_t)blockIdx.x * OUT_FLOATS_PER_BLOCK);
    const f32x4* __restrict__ s4 = (const f32x4*)so;
#pragma unroll
    for (int i = 0; i < 4; ++i) {
        outv[t + THREADS * i] = s4[t + THREADS * i];
    }
    if (t < OUT_F4_PER_BLOCK - 4 * THREADS) {           // 128 remainder slots
        outv[t + 4 * THREADS] = s4[t + 4 * THREADS];
    }
}

extern "C" void kernel_launch(void* const* d_in, const int* in_sizes, int n_in,
                              void* d_out, int out_size, void* d_ws, size_t ws_size,
                              hipStream_t stream) {
    const float* x = (const float*)d_in[0];   // 27 floats
    const float* w = (const float*)d_in[1];   // 2048*2048*3 floats
    float* out = (float*)d_out;               // 2048*2048*9 floats

    const int pairs = 2048 * 2048;                    // 4,194,304
    const int blocks = pairs / PAIRS_PER_BLOCK;       // 8192, exact cover
    gf_kernel<<<blocks, THREADS, 0, stream>>>(x, w, out);
}